// Round 1
// baseline (20970.143 us; speedup 1.0000x reference)
//
#include <hip/hip_runtime.h>

#define T_LEN 1024
#define DIN   512
#define HID   1024
#define NWG   64   // 32 WGs for layer0 + 32 for layer1

typedef __attribute__((ext_vector_type(8))) short short8;  // 8 x bf16 bits (MFMA frag)
typedef __attribute__((ext_vector_type(4))) float f4;

__device__ __forceinline__ unsigned short f2bf(float f) {
  union { float f; unsigned u; } v; v.f = f;
  return (unsigned short)((v.u + 0x7FFFu + ((v.u >> 16) & 1u)) >> 16);  // RNE
}
__device__ __forceinline__ float bf2f(unsigned short b) {
  union { unsigned u; float f; } v; v.u = ((unsigned)b) << 16; return v.f;
}
__device__ __forceinline__ short8 cvt8(f4 a, f4 b) {
  short8 r;
  r[0]=(short)f2bf(a[0]); r[1]=(short)f2bf(a[1]); r[2]=(short)f2bf(a[2]); r[3]=(short)f2bf(a[3]);
  r[4]=(short)f2bf(b[0]); r[5]=(short)f2bf(b[1]); r[6]=(short)f2bf(b[2]); r[7]=(short)f2bf(b[3]);
  return r;
}
__device__ __forceinline__ float tanh_fast(float x) {
  float e = __expf(2.f * x);           // exp overflow -> inf -> returns 1; -inf -> -1. OK.
  return 1.f - 2.f / (e + 1.f);
}
__device__ __forceinline__ f4 mfma16(short8 a, short8 b, f4 c) {
  return __builtin_amdgcn_mfma_f32_16x16x32_bf16(a, b, c, 0, 0, 0);
}

// ---- prep: compute lo-residual of W_hh (bf16 pair trick) + zero h-state and barrier flags ----
__global__ void prep_kernel(const float* __restrict__ Whh0, const float* __restrict__ Whh1,
                            unsigned short* __restrict__ wlo0, unsigned short* __restrict__ wlo1,
                            unsigned int* __restrict__ zero_base) {
  int i = blockIdx.x * 256 + threadIdx.x;          // grid covers 1024*1024
  float w0 = Whh0[i];
  wlo0[i] = f2bf(w0 - bf2f(f2bf(w0)));
  float w1 = Whh1[i];
  wlo1[i] = f2bf(w1 - bf2f(f2bf(w1)));
  if (i < 133120) zero_base[i] = 0u;               // h0b+h1b (131072 u32) + flags (2048 u32)
}

// ---- grid barrier: padded flag per WG, monotone step counter, one-wave parallel poll ----
__device__ __forceinline__ void gridbar(int* flags, int expect) {
  __threadfence();
  __syncthreads();
  if (threadIdx.x == 0)
    __hip_atomic_store(flags + blockIdx.x * 32, expect, __ATOMIC_RELEASE, __HIP_MEMORY_SCOPE_AGENT);
  if (threadIdx.x < NWG) {
    const int* f = flags + threadIdx.x * 32;
    while (__hip_atomic_load(f, __ATOMIC_RELAXED, __HIP_MEMORY_SCOPE_AGENT) < expect)
      __builtin_amdgcn_s_sleep(1);
  }
  __threadfence();
  __syncthreads();
}

// ---- fused persistent 2-layer RNN, layer1 pipelined one step behind layer0 ----
// WG wg: layer = wg>>5, output cols [ (wg&31)*32, +32 ).  4 waves split K (256 each),
// weights held in registers (B-frags hoisted), partials reduced via LDS.
__global__ __launch_bounds__(256, 2)
void rnn_fused(const float* __restrict__ x,
               const float* __restrict__ Wih0, const float* __restrict__ Whh0,
               const float* __restrict__ bi0,  const float* __restrict__ bh0,
               const float* __restrict__ Wih1, const float* __restrict__ Whh1,
               const float* __restrict__ bi1,  const float* __restrict__ bh1,
               const unsigned short* __restrict__ wlo0, const unsigned short* __restrict__ wlo1,
               unsigned short* __restrict__ h0b, unsigned short* __restrict__ h1b,
               unsigned short* __restrict__ y0b, int* __restrict__ flags,
               float* __restrict__ outy, float* __restrict__ outh) {
  const int wg    = blockIdx.x;
  const int layer = wg >> 5;
  const int i_base = (wg & 31) * 32;
  const int tid  = threadIdx.x;
  const int wv   = tid >> 6;        // wave id = K-quarter
  const int lane = tid & 63;
  const int l15  = lane & 15;
  const int kb   = lane >> 4;       // k-block within 32 (8 elems each)

  const float* Wih = layer ? Wih1 : Wih0;
  const float* Whh = layer ? Whh1 : Whh0;
  const unsigned short* wloL = layer ? wlo1 : wlo0;
  const int K1   = layer ? HID : DIN;
  const int KQ   = K1 >> 2;         // per-wave K range for the input projection
  const int npre = KQ >> 5;         // 4 (layer0) or 8 (layer1)
  unsigned short* hb = layer ? h1b : h0b;   // [parity][hi/lo][32*1024]

  __shared__ float red[4][4][64][4];        // [wave][frag][lane][reg] 16 KB

  // ---- hoist weight B-fragments into registers (read once) ----
  // frag layout: lane = n(l15) + 16*kblock(kb); 8 contiguous k per lane (row-major [n][k]).
  short8 bpre[8][2];                 // W_ih slice (bf16), [kk][nf]
  short8 brhi[8][2];                 // W_hh hi slice,     [kk][nf]
#pragma unroll
  for (int kk = 0; kk < 8; ++kk) {
#pragma unroll
    for (int nfj = 0; nfj < 2; ++nfj) {
      if (kk < npre) {
        int k = wv * KQ + kk * 32 + kb * 8;
        const float* s = Wih + (size_t)(i_base + nfj * 16 + l15) * K1 + k;
        bpre[kk][nfj] = cvt8(*(const f4*)s, *(const f4*)(s + 4));
      }
      {
        int k = wv * 256 + kk * 32 + kb * 8;
        const float* s = Whh + (size_t)(i_base + nfj * 16 + l15) * HID + k;
        f4 a = *(const f4*)s; f4 b = *(const f4*)(s + 4);
        short8 hi;
#pragma unroll
        for (int j = 0; j < 4; ++j) { hi[j]   = (short)f2bf(a[j]); }
#pragma unroll
        for (int j = 0; j < 4; ++j) { hi[4+j] = (short)f2bf(b[j]); }
        brhi[kk][nfj] = hi;
      }
    }
  }

  // epilogue constants: this wave finalizes frag f=wv -> (mh, nf)
  const int emh = wv & 1, enf = wv >> 1;
  const int e_i = i_base + enf * 16 + l15;                 // global output col
  const float biasv = layer ? (bi1[e_i] + bh1[e_i]) : (bi0[e_i] + bh0[e_i]);

  for (int s = 0; s <= T_LEN; ++s) {
    const bool active = layer ? (s >= 1) : (s < T_LEN);
    if (active) {
      const int t = layer ? (s - 1) : s;
      f4 acc0 = {0.f,0.f,0.f,0.f}, acc1 = acc0, acc2 = acc0, acc3 = acc0;

      // ---- input projection part (A = x[.,t,.] fp32  or  y0[.,t,.] bf16) ----
      if (layer == 0) {
        const float* xr0 = x + ((size_t)l15 * T_LEN + t) * DIN;
        const float* xr1 = x + ((size_t)(16 + l15) * T_LEN + t) * DIN;
#pragma unroll
        for (int kk = 0; kk < 4; ++kk) {
          int k = wv * 128 + kk * 32 + kb * 8;
          short8 a0 = cvt8(*(const f4*)(xr0 + k), *(const f4*)(xr0 + k + 4));
          short8 a1 = cvt8(*(const f4*)(xr1 + k), *(const f4*)(xr1 + k + 4));
          acc0 = mfma16(a0, bpre[kk][0], acc0);
          acc1 = mfma16(a1, bpre[kk][0], acc1);
          acc2 = mfma16(a0, bpre[kk][1], acc2);
          acc3 = mfma16(a1, bpre[kk][1], acc3);
        }
      } else {
        const unsigned short* yc = y0b + (size_t)(t & 1) * 32768;
#pragma unroll
        for (int kk = 0; kk < 8; ++kk) {
          int k = wv * 256 + kk * 32 + kb * 8;
          short8 a0 = *(const short8*)(yc + (size_t)l15 * HID + k);
          short8 a1 = *(const short8*)(yc + (size_t)(16 + l15) * HID + k);
          acc0 = mfma16(a0, bpre[kk][0], acc0);
          acc1 = mfma16(a1, bpre[kk][0], acc1);
          acc2 = mfma16(a0, bpre[kk][1], acc2);
          acc3 = mfma16(a1, bpre[kk][1], acc3);
        }
      }

      // ---- recurrent part: 3-term hi/lo compensated bf16 (h_hi*W_hi + h_lo*W_hi + h_hi*W_lo) ----
      {
        const unsigned short* hhi = hb + (size_t)((t & 1) * 2 + 0) * 32768;
        const unsigned short* hlo = hb + (size_t)((t & 1) * 2 + 1) * 32768;
#pragma unroll
        for (int kk = 0; kk < 8; ++kk) {
          int k = wv * 256 + kk * 32 + kb * 8;
          short8 ah0 = *(const short8*)(hhi + (size_t)l15 * HID + k);
          short8 ah1 = *(const short8*)(hhi + (size_t)(16 + l15) * HID + k);
          short8 al0 = *(const short8*)(hlo + (size_t)l15 * HID + k);
          short8 al1 = *(const short8*)(hlo + (size_t)(16 + l15) * HID + k);
          const unsigned short* w0p = wloL + (size_t)(i_base + l15) * HID + k;
          const unsigned short* w1p = wloL + (size_t)(i_base + 16 + l15) * HID + k;
          short8 bl0 = *(const short8*)w0p;
          short8 bl1 = *(const short8*)w1p;
          acc0 = mfma16(ah0, brhi[kk][0], acc0);
          acc1 = mfma16(ah1, brhi[kk][0], acc1);
          acc2 = mfma16(ah0, brhi[kk][1], acc2);
          acc3 = mfma16(ah1, brhi[kk][1], acc3);
          acc0 = mfma16(al0, brhi[kk][0], acc0);
          acc1 = mfma16(al1, brhi[kk][0], acc1);
          acc2 = mfma16(al0, brhi[kk][1], acc2);
          acc3 = mfma16(al1, brhi[kk][1], acc3);
          acc0 = mfma16(ah0, bl0, acc0);
          acc1 = mfma16(ah1, bl0, acc1);
          acc2 = mfma16(ah0, bl1, acc2);
          acc3 = mfma16(ah1, bl1, acc3);
        }
      }

      // ---- cross-wave K reduction via LDS ----
      *(f4*)&red[wv][0][lane][0] = acc0;
      *(f4*)&red[wv][1][lane][0] = acc1;
      *(f4*)&red[wv][2][lane][0] = acc2;
      *(f4*)&red[wv][3][lane][0] = acc3;
      __syncthreads();
      f4 tot = *(const f4*)&red[0][wv][lane][0];
      tot += *(const f4*)&red[1][wv][lane][0];
      tot += *(const f4*)&red[2][wv][lane][0];
      tot += *(const f4*)&red[3][wv][lane][0];

      // ---- epilogue: bias + tanh, store h (hi/lo), y0 ring / final outputs ----
      // C/D layout: col = lane&15, row = (lane>>4)*4 + reg  [m89]
      unsigned short* nh_hi = hb + (size_t)(((t + 1) & 1) * 2 + 0) * 32768;
      unsigned short* nh_lo = hb + (size_t)(((t + 1) & 1) * 2 + 1) * 32768;
      const int prow = emh * 16 + kb * 4;
#pragma unroll
      for (int rr = 0; rr < 4; ++rr) {
        const int b = prow + rr;
        float v = tanh_fast(tot[rr] + biasv);
        unsigned short hi = f2bf(v);
        unsigned short lo = f2bf(v - bf2f(hi));
        nh_hi[(size_t)b * HID + e_i] = hi;
        nh_lo[(size_t)b * HID + e_i] = lo;
        if (layer == 0) {
          y0b[(size_t)(t & 1) * 32768 + (size_t)b * HID + e_i] = hi;
          if (t == T_LEN - 1) outh[(size_t)b * HID + e_i] = v;
        } else {
          outy[((size_t)b * T_LEN + t) * HID + e_i] = v;
          if (t == T_LEN - 1) outh[32768 + (size_t)b * HID + e_i] = v;
        }
      }
    }
    if (s < T_LEN) gridbar(flags, s + 1);
  }
}

extern "C" void kernel_launch(void* const* d_in, const int* in_sizes, int n_in,
                              void* d_out, int out_size, void* d_ws, size_t ws_size,
                              hipStream_t stream) {
  const float* x    = (const float*)d_in[0];
  const float* Wih0 = (const float*)d_in[1];
  const float* Whh0 = (const float*)d_in[2];
  const float* bi0  = (const float*)d_in[3];
  const float* bh0  = (const float*)d_in[4];
  const float* Wih1 = (const float*)d_in[5];
  const float* Whh1 = (const float*)d_in[6];
  const float* bi1  = (const float*)d_in[7];
  const float* bh1  = (const float*)d_in[8];

  float* outy = (float*)d_out;
  float* outh = outy + (size_t)32 * 1024 * 1024;   // [2][32][1024] tail

  char* ws = (char*)d_ws;
  unsigned short* wlo0 = (unsigned short*)(ws);                    // 1024*1024 bf16 = 2 MB
  unsigned short* wlo1 = (unsigned short*)(ws + 2097152);          // 2 MB
  unsigned short* h0b  = (unsigned short*)(ws + 4194304);          // [2][2][32768] = 256 KB
  unsigned short* h1b  = (unsigned short*)(ws + 4456448);          // 256 KB
  int*            flg  = (int*)           (ws + 4718592);          // 64*32 ints = 8 KB
  unsigned short* y0b  = (unsigned short*)(ws + 4726784);          // [2][32768] = 128 KB
  unsigned int* zero_base = (unsigned int*)h0b;                    // h0b+h1b+flags contiguous

  prep_kernel<<<4096, 256, 0, stream>>>(Whh0, Whh1, wlo0, wlo1, zero_base);
  rnn_fused<<<NWG, 256, 0, stream>>>(x, Wih0, Whh0, bi0, bh0,
                                     Wih1, Whh1, bi1, bh1,
                                     wlo0, wlo1, h0b, h1b, y0b, flg,
                                     outy, outh);
}

// Round 2
// 8913.045 us; speedup vs baseline: 2.3527x; 2.3527x over previous
//
#include <hip/hip_runtime.h>

#define T_LEN 1024
#define DIN   512
#define HID   1024
#define NWG   64   // 32 WGs layer0 + 32 WGs layer1

typedef __attribute__((ext_vector_type(8))) short short8;  // 8 x bf16 bits (MFMA frag)
typedef __attribute__((ext_vector_type(4))) float f4;

__device__ __forceinline__ unsigned short f2bf(float f) {
  union { float f; unsigned u; } v; v.f = f;
  return (unsigned short)((v.u + 0x7FFFu + ((v.u >> 16) & 1u)) >> 16);  // RNE
}
__device__ __forceinline__ float bf2f(unsigned short b) {
  union { unsigned u; float f; } v; v.u = ((unsigned)b) << 16; return v.f;
}
__device__ __forceinline__ short8 cvt8(f4 a, f4 b) {
  short8 r;
  r[0]=(short)f2bf(a[0]); r[1]=(short)f2bf(a[1]); r[2]=(short)f2bf(a[2]); r[3]=(short)f2bf(a[3]);
  r[4]=(short)f2bf(b[0]); r[5]=(short)f2bf(b[1]); r[6]=(short)f2bf(b[2]); r[7]=(short)f2bf(b[3]);
  return r;
}
// fp32x8 -> bf16 hi + bf16 residual(lo)
__device__ __forceinline__ void cvt8hl(f4 a, f4 b, short8& hi, short8& lo) {
  hi = cvt8(a, b);
  f4 ra, rb;
#pragma unroll
  for (int j = 0; j < 4; ++j) {
    ra[j] = a[j] - bf2f((unsigned short)hi[j]);
    rb[j] = b[j] - bf2f((unsigned short)hi[4 + j]);
  }
  lo = cvt8(ra, rb);
}
__device__ __forceinline__ float tanh_fast(float x) {
  float e = __expf(2.f * x);
  return 1.f - 2.f / (e + 1.f);
}
__device__ __forceinline__ f4 mfma16(short8 a, short8 b, f4 c) {
  return __builtin_amdgcn_mfma_f32_16x16x32_bf16(a, b, c, 0, 0, 0);
}
// 3-term compensated bf16 product: (ah+al)*(bh+bl) ~= ah*bh + al*bh + ah*bl
__device__ __forceinline__ f4 fma3(short8 ah, short8 al, short8 bh, short8 bl, f4 c) {
  c = mfma16(ah, bh, c);
  c = mfma16(al, bh, c);
  c = mfma16(ah, bl, c);
  return c;
}

// Coherent (agent-scope, L1/L2-bypassing) coalesced fragment load.
// Layout: element j of this lane's fragment lives at p + j*64 (lane-fastest).
// One u32 = packed (lo16<<16)|hi16 of h.
__device__ __forceinline__ void load_pk8f(const unsigned int* p, short8& hi, short8& lo) {
  unsigned int r[8];
#pragma unroll
  for (int j = 0; j < 8; ++j)
    r[j] = __hip_atomic_load((unsigned int*)(p + (size_t)j * 64),
                             __ATOMIC_RELAXED, __HIP_MEMORY_SCOPE_AGENT);
#pragma unroll
  for (int j = 0; j < 8; ++j) {
    hi[j] = (short)(r[j] & 0xffffu);
    lo[j] = (short)(r[j] >> 16);
  }
}

// Zero h0pk + h1pk + flags (520 KB = 133120 u32, contiguous at ws base).
__global__ void prep_kernel(unsigned int* __restrict__ z) {
  z[blockIdx.x * 256 + threadIdx.x] = 0u;
}

// Fence-free grid barrier: all cross-WG data uses agent-scope write-through
// stores, so visibility only needs vmcnt(0) before the (relaxed) flag store.
// No buffer_wbl2 / buffer_inv — private cached data (x, outy lines) stays hot.
__device__ __forceinline__ void gridbar(int* flags, int expect) {
  __syncthreads();                                   // drains each wave's vmem (compiler waitcnt)
  asm volatile("s_waitcnt vmcnt(0)" ::: "memory");
  if (threadIdx.x == 0)
    __hip_atomic_store(flags + blockIdx.x * 32, expect,
                       __ATOMIC_RELAXED, __HIP_MEMORY_SCOPE_AGENT);
  if (threadIdx.x < NWG) {
    int* f = flags + threadIdx.x * 32;
    while (__hip_atomic_load(f, __ATOMIC_RELAXED, __HIP_MEMORY_SCOPE_AGENT) < expect)
      __builtin_amdgcn_s_sleep(1);
  }
  __syncthreads();
}

// Persistent fused 2-layer RNN. WG wg: layer=wg>>5, output cols [(wg&31)*32,+32).
// 4 waves split K. All weights (hi+lo bf16 pairs) live in registers.
// h state: packed u32 (hi|lo<<16), stored in MFMA-fragment order, lane-fastest:
//   flat = (((k>>8)*8 + ((k>>5)&7))*2 + (b>>4))*512 + (k&7)*64 + ((k>>3)&3)*16 + (b&15)
__global__ __launch_bounds__(256, 1)
void rnn_fused(const float* __restrict__ x,
               const float* __restrict__ Wih0, const float* __restrict__ Whh0,
               const float* __restrict__ bi0,  const float* __restrict__ bh0,
               const float* __restrict__ Wih1, const float* __restrict__ Whh1,
               const float* __restrict__ bi1,  const float* __restrict__ bh1,
               unsigned int* __restrict__ h0pk, unsigned int* __restrict__ h1pk,
               int* __restrict__ flags,
               float* __restrict__ outy, float* __restrict__ outh) {
  const int wg    = blockIdx.x;
  const int layer = wg >> 5;
  const int i_base = (wg & 31) * 32;
  const int tid  = threadIdx.x;
  const int wv   = tid >> 6;        // wave id = K-quarter
  const int lane = tid & 63;
  const int l15  = lane & 15;
  const int kb   = lane >> 4;       // k-block within 32 (8 elems each)

  const float* Wih = layer ? Wih1 : Wih0;
  const float* Whh = layer ? Whh1 : Whh0;
  const int K1   = layer ? HID : DIN;
  const int npre = layer ? 8 : 4;
  unsigned int* hpk = layer ? h1pk : h0pk;

  __shared__ float red[4][4][64][4];   // [wave][frag][lane][reg] 16 KB

  // ---- hoist all weights to registers as bf16 hi/lo pairs (read once) ----
  short8 bpre[8][2], bprl[8][2], brhi[8][2], brlo[8][2];
#pragma unroll
  for (int kk = 0; kk < 8; ++kk) {
#pragma unroll
    for (int nfj = 0; nfj < 2; ++nfj) {
      if (kk < npre) {
        int k = wv * (K1 >> 2) + kk * 32 + kb * 8;
        const float* sp = Wih + (size_t)(i_base + nfj * 16 + l15) * K1 + k;
        cvt8hl(*(const f4*)sp, *(const f4*)(sp + 4), bpre[kk][nfj], bprl[kk][nfj]);
      }
      {
        int k = wv * 256 + kk * 32 + kb * 8;
        const float* sp = Whh + (size_t)(i_base + nfj * 16 + l15) * HID + k;
        cvt8hl(*(const f4*)sp, *(const f4*)(sp + 4), brhi[kk][nfj], brlo[kk][nfj]);
      }
    }
  }

  const int emh = wv & 1, enf = wv >> 1;      // this wave finalizes frag wv
  const int e_i = i_base + enf * 16 + l15;    // global output col
  const float biasv = layer ? (bi1[e_i] + bh1[e_i]) : (bi0[e_i] + bh0[e_i]);
  // producer scatter base into fragment-ordered layout (rr adds +0..3)
  const int pbase = ((((e_i >> 8) * 8 + ((e_i >> 5) & 7)) * 2 + emh) * 8 + (e_i & 7)) * 64
                    + ((e_i >> 3) & 3) * 16 + kb * 4;

  for (int s = 0; s <= T_LEN; ++s) {
    const bool active = layer ? (s >= 1) : (s < T_LEN);
    if (active) {
      const int t = layer ? (s - 1) : s;
      f4 acc0 = {0.f,0.f,0.f,0.f}, acc1 = acc0, acc2 = acc0, acc3 = acc0;

      // ---- input projection (hi/lo compensated on both A and B) ----
      if (layer == 0) {
        const float* xr0 = x + ((size_t)l15 * T_LEN + t) * DIN;
        const float* xr1 = x + ((size_t)(16 + l15) * T_LEN + t) * DIN;
#pragma unroll
        for (int kk = 0; kk < 4; ++kk) {
          int k = wv * 128 + kk * 32 + kb * 8;
          short8 a0h, a0l, a1h, a1l;
          cvt8hl(*(const f4*)(xr0 + k), *(const f4*)(xr0 + k + 4), a0h, a0l);
          cvt8hl(*(const f4*)(xr1 + k), *(const f4*)(xr1 + k + 4), a1h, a1l);
          acc0 = fma3(a0h, a0l, bpre[kk][0], bprl[kk][0], acc0);
          acc1 = fma3(a1h, a1l, bpre[kk][0], bprl[kk][0], acc1);
          acc2 = fma3(a0h, a0l, bpre[kk][1], bprl[kk][1], acc2);
          acc3 = fma3(a1h, a1l, bpre[kk][1], bprl[kk][1], acc3);
        }
      } else {
        // y0[t] == layer0 state written at its step t into parity (t+1)&1
        const unsigned int* yc = h0pk + (size_t)((t + 1) & 1) * 32768;
#pragma unroll
        for (int kk = 0; kk < 8; ++kk) {
          const unsigned int* pb = yc + (size_t)(wv * 8 + kk) * 1024 + kb * 16 + l15;
          short8 a0h, a0l, a1h, a1l;
          load_pk8f(pb,       a0h, a0l);
          load_pk8f(pb + 512, a1h, a1l);
          acc0 = fma3(a0h, a0l, bpre[kk][0], bprl[kk][0], acc0);
          acc1 = fma3(a1h, a1l, bpre[kk][0], bprl[kk][0], acc1);
          acc2 = fma3(a0h, a0l, bpre[kk][1], bprl[kk][1], acc2);
          acc3 = fma3(a1h, a1l, bpre[kk][1], bprl[kk][1], acc3);
        }
      }

      // ---- recurrent part ----
      {
        const unsigned int* hc = hpk + (size_t)(t & 1) * 32768;
#pragma unroll
        for (int kk = 0; kk < 8; ++kk) {
          const unsigned int* pb = hc + (size_t)(wv * 8 + kk) * 1024 + kb * 16 + l15;
          short8 a0h, a0l, a1h, a1l;
          load_pk8f(pb,       a0h, a0l);
          load_pk8f(pb + 512, a1h, a1l);
          acc0 = fma3(a0h, a0l, brhi[kk][0], brlo[kk][0], acc0);
          acc1 = fma3(a1h, a1l, brhi[kk][0], brlo[kk][0], acc1);
          acc2 = fma3(a0h, a0l, brhi[kk][1], brlo[kk][1], acc2);
          acc3 = fma3(a1h, a1l, brhi[kk][1], brlo[kk][1], acc3);
        }
      }

      // ---- cross-wave K reduction via LDS ----
      *(f4*)&red[wv][0][lane][0] = acc0;
      *(f4*)&red[wv][1][lane][0] = acc1;
      *(f4*)&red[wv][2][lane][0] = acc2;
      *(f4*)&red[wv][3][lane][0] = acc3;
      __syncthreads();
      f4 tot = *(const f4*)&red[0][wv][lane][0];
      tot += *(const f4*)&red[1][wv][lane][0];
      tot += *(const f4*)&red[2][wv][lane][0];
      tot += *(const f4*)&red[3][wv][lane][0];

      // ---- epilogue: bias + tanh; coherent packed h store; outputs ----
      // C/D layout: col = lane&15, row = (lane>>4)*4 + reg  [m89]
      unsigned int* nh = hpk + (size_t)((t + 1) & 1) * 32768;
      const int prow = emh * 16 + kb * 4;
#pragma unroll
      for (int rr = 0; rr < 4; ++rr) {
        const int b = prow + rr;
        float v = tanh_fast(tot[rr] + biasv);
        unsigned short hi = f2bf(v);
        unsigned short lo = f2bf(v - bf2f(hi));
        unsigned int pk = (unsigned int)hi | ((unsigned int)lo << 16);
        __hip_atomic_store(nh + pbase + rr, pk,
                           __ATOMIC_RELAXED, __HIP_MEMORY_SCOPE_AGENT);
        if (layer == 0) {
          if (t == T_LEN - 1) outh[(size_t)b * HID + e_i] = v;
        } else {
          outy[((size_t)b * T_LEN + t) * HID + e_i] = v;
          if (t == T_LEN - 1) outh[32768 + (size_t)b * HID + e_i] = v;
        }
      }
    }
    if (s < T_LEN) gridbar(flags, s + 1);
  }
}

extern "C" void kernel_launch(void* const* d_in, const int* in_sizes, int n_in,
                              void* d_out, int out_size, void* d_ws, size_t ws_size,
                              hipStream_t stream) {
  const float* x    = (const float*)d_in[0];
  const float* Wih0 = (const float*)d_in[1];
  const float* Whh0 = (const float*)d_in[2];
  const float* bi0  = (const float*)d_in[3];
  const float* bh0  = (const float*)d_in[4];
  const float* Wih1 = (const float*)d_in[5];
  const float* Whh1 = (const float*)d_in[6];
  const float* bi1  = (const float*)d_in[7];
  const float* bh1  = (const float*)d_in[8];

  float* outy = (float*)d_out;
  float* outh = outy + (size_t)32 * 1024 * 1024;   // [2][32][1024] tail

  char* ws = (char*)d_ws;
  unsigned int* h0pk = (unsigned int*)ws;              // [2][32768] u32 = 256 KB
  unsigned int* h1pk = (unsigned int*)(ws + 262144);   // 256 KB
  int*          flg  = (int*)(ws + 524288);            // 64*32 ints = 8 KB

  prep_kernel<<<520, 256, 0, stream>>>((unsigned int*)ws);   // zero 520 KB
  rnn_fused<<<NWG, 256, 0, stream>>>(x, Wih0, Whh0, bi0, bh0,
                                     Wih1, Whh1, bi1, bh1,
                                     h0pk, h1pk, flg, outy, outh);
}